// Round 2
// baseline (8587.402 us; speedup 1.0000x reference)
//
#include <hip/hip_runtime.h>
#include <hip/hip_bf16.h>

#define L_LAYERS 10
#define NN 10000
#define EE 160000
#define HH 128

__device__ __forceinline__ float gelu_exact(float x) {
  return 0.5f * x * (1.0f + erff(x * 0.7071067811865475f));
}

// ---------------- encoder: h = gelu(LN(x @ W + b)) ----------------
__global__ __launch_bounds__(128) void k_encoder(
    const float* __restrict__ x, const float* __restrict__ W,
    const float* __restrict__ b, const float* __restrict__ g,
    const float* __restrict__ bt, float* __restrict__ h)
{
  const int n = blockIdx.x;
  const int j = threadIdx.x; // 128
  __shared__ float xs[7];
  __shared__ float red[4];
  if (j < 7) xs[j] = x[n * 7 + j];
  __syncthreads();
  float z = b[j];
  #pragma unroll
  for (int k = 0; k < 7; ++k) z = fmaf(xs[k], W[k * 128 + j], z);
  float sm = z, sq = z * z;
  #pragma unroll
  for (int off = 32; off > 0; off >>= 1) {
    sm += __shfl_down(sm, off);
    sq += __shfl_down(sq, off);
  }
  const int wv = j >> 6, ln = j & 63;
  if (ln == 0) { red[wv] = sm; red[2 + wv] = sq; }
  __syncthreads();
  float m = (red[0] + red[1]) * (1.0f / 128.0f);
  float var = (red[2] + red[3]) * (1.0f / 128.0f) - m * m;
  float zz = (z - m) * rsqrtf(var + 1e-5f) * g[j] + bt[j];
  h[(size_t)n * 128 + j] = gelu_exact(zz);
}

// ---------------- edge encoder: e = ea @ W + b ----------------
__global__ __launch_bounds__(256) void k_edge_enc(
    const float* __restrict__ ea, const float* __restrict__ W,
    const float* __restrict__ b, float* __restrict__ e)
{
  const int i = blockIdx.x * 256 + threadIdx.x; // over EE*128
  const int eid = i >> 7, j = i & 127;
  float z = b[j];
  #pragma unroll
  for (int k = 0; k < 8; ++k) z = fmaf(ea[eid * 8 + k], W[k * 128 + j], z);
  e[i] = z;
}

// ---------------- CSR build ----------------
__global__ void k_zero_cnt(int* __restrict__ cnt) {
  int i = blockIdx.x * 256 + threadIdx.x;
  if (i < NN) cnt[i] = 0;
}
__global__ void k_count(const int* __restrict__ eidx, int* __restrict__ cnt) {
  int i = blockIdx.x * 256 + threadIdx.x;
  atomicAdd(&cnt[eidx[EE + i]], 1);
}
__global__ __launch_bounds__(256) void k_scan(
    const int* __restrict__ cnt, int* __restrict__ rowptr, int* __restrict__ fillp)
{
  __shared__ int tot[256];
  __shared__ int off[257];
  const int t = threadIdx.x;
  const int C = 40; // 256*40 = 10240 >= NN
  int s = 0;
  int lo = t * C, hi = lo + C; if (hi > NN) hi = NN;
  for (int i = lo; i < hi; ++i) s += cnt[i];
  tot[t] = s;
  __syncthreads();
  if (t == 0) {
    int r = 0;
    for (int i = 0; i < 256; ++i) { off[i] = r; r += tot[i]; }
    off[256] = r;
  }
  __syncthreads();
  int r = off[t];
  for (int i = lo; i < hi; ++i) {
    rowptr[i] = r; fillp[i] = r;
    r += cnt[i];
  }
  if (t == 0) rowptr[NN] = off[256];
}
__global__ void k_fill(const int* __restrict__ eidx, int* __restrict__ fillp,
                       int* __restrict__ edge_of) {
  int i = blockIdx.x * 256 + threadIdx.x;
  int c = eidx[EE + i];
  int pos = atomicAdd(&fillp[c], 1);
  edge_of[pos] = i;
}

// ---------------- aggregation: agg[n] = mean of e over CSR ----------------
__global__ __launch_bounds__(128) void k_agg(
    const float* __restrict__ e, const int* __restrict__ rowptr,
    const int* __restrict__ edge_of, float* __restrict__ agg)
{
  const int n = blockIdx.x;
  const int j = threadIdx.x; // 128
  const int s = rowptr[n], en = rowptr[n + 1];
  float acc = 0.0f;
  for (int it = s; it < en; ++it) {
    int eid = edge_of[it];
    acc += e[(size_t)eid * 128 + j];
  }
  int c = en - s;
  float inv = 1.0f / (float)(c > 0 ? c : 1);
  agg[(size_t)n * 128 + j] = acc * inv;
}

// ---------------- edge MLP: e += LN(GELU(LN(in@W1+b1))@W2+b2) ----------------
__global__ __launch_bounds__(256) void k_edge_mlp(
    const float* __restrict__ h, float* __restrict__ e,
    const int* __restrict__ eidx,
    const float* __restrict__ W1, const float* __restrict__ b1,
    const float* __restrict__ g1, const float* __restrict__ bt1,
    const float* __restrict__ W2, const float* __restrict__ b2,
    const float* __restrict__ g2, const float* __restrict__ bt2,
    int layer)
{
  __shared__ float A[16 * 384];
  __shared__ float Z1[16 * 256];
  __shared__ float Z2[16 * 128];
  __shared__ float mu1[16], rs1[16], mu2[16], rs2[16];
  __shared__ int s_row[16], s_col[16];

  const int tid = threadIdx.x;
  const int base = blockIdx.x * 16;
  const float* W1p = W1 + (size_t)layer * 384 * 256;
  const float* W2p = W2 + (size_t)layer * 256 * 128;
  const float* b1p = b1 + layer * 256;
  const float* g1p = g1 + layer * 256;
  const float* bt1p = bt1 + layer * 256;
  const float* b2p = b2 + layer * 128;
  const float* g2p = g2 + layer * 128;
  const float* bt2p = bt2 + layer * 128;

  if (tid < 16) s_row[tid] = eidx[base + tid];
  else if (tid < 32) s_col[tid - 16] = eidx[EE + base + (tid - 16)];
  __syncthreads();

  for (int idx = tid; idx < 16 * 384; idx += 256) {
    int ei = idx / 384;
    int c = idx - ei * 384;
    float v;
    if (c < 128)      v = h[(size_t)s_row[ei] * 128 + c];
    else if (c < 256) v = h[(size_t)s_col[ei] * 128 + (c - 128)];
    else              v = e[(size_t)(base + ei) * 128 + (c - 256)];
    A[idx] = v;
  }
  __syncthreads();

  // GEMM1: [16x384] @ [384x256] -> Z1
  {
    const int oc = tid & 127;
    const int ehf = tid >> 7; // 0..1, 8 edges each
    float acc0[8], acc1[8];
    #pragma unroll
    for (int s = 0; s < 8; ++s) { acc0[s] = 0.f; acc1[s] = 0.f; }
    for (int k4 = 0; k4 < 384; k4 += 4) {
      float w0[4], w1[4];
      #pragma unroll
      for (int u = 0; u < 4; ++u) {
        w0[u] = W1p[(k4 + u) * 256 + oc];
        w1[u] = W1p[(k4 + u) * 256 + oc + 128];
      }
      #pragma unroll
      for (int s = 0; s < 8; ++s) {
        const float4 a = *(const float4*)&A[(ehf * 8 + s) * 384 + k4];
        acc0[s] = fmaf(a.x, w0[0], acc0[s]); acc0[s] = fmaf(a.y, w0[1], acc0[s]);
        acc0[s] = fmaf(a.z, w0[2], acc0[s]); acc0[s] = fmaf(a.w, w0[3], acc0[s]);
        acc1[s] = fmaf(a.x, w1[0], acc1[s]); acc1[s] = fmaf(a.y, w1[1], acc1[s]);
        acc1[s] = fmaf(a.z, w1[2], acc1[s]); acc1[s] = fmaf(a.w, w1[3], acc1[s]);
      }
    }
    float bb0 = b1p[oc], bb1 = b1p[oc + 128];
    #pragma unroll
    for (int s = 0; s < 8; ++s) {
      Z1[(ehf * 8 + s) * 256 + oc] = acc0[s] + bb0;
      Z1[(ehf * 8 + s) * 256 + oc + 128] = acc1[s] + bb1;
    }
  }
  __syncthreads();

  // LN1 stats (256 per edge)
  {
    const int wv = tid >> 6, ln = tid & 63;
    for (int s = 0; s < 4; ++s) {
      int ei = wv * 4 + s;
      float v0 = Z1[ei * 256 + ln], v1 = Z1[ei * 256 + ln + 64];
      float v2 = Z1[ei * 256 + ln + 128], v3 = Z1[ei * 256 + ln + 192];
      float sm = v0 + v1 + v2 + v3;
      float sq = v0 * v0 + v1 * v1 + v2 * v2 + v3 * v3;
      #pragma unroll
      for (int off = 32; off > 0; off >>= 1) {
        sm += __shfl_down(sm, off);
        sq += __shfl_down(sq, off);
      }
      if (ln == 0) {
        float m = sm * (1.f / 256.f);
        float var = sq * (1.f / 256.f) - m * m;
        mu1[ei] = m; rs1[ei] = rsqrtf(var + 1e-5f);
      }
    }
  }
  __syncthreads();

  // normalize + gelu in place
  {
    float g = g1p[tid], bt = bt1p[tid];
    for (int ei = 0; ei < 16; ++ei) {
      float z = Z1[ei * 256 + tid];
      z = (z - mu1[ei]) * rs1[ei] * g + bt;
      Z1[ei * 256 + tid] = gelu_exact(z);
    }
  }
  __syncthreads();

  // GEMM2: [16x256] @ [256x128] -> Z2
  {
    const int c2 = tid & 63;
    const int eq = tid >> 6; // 0..3, 4 edges each
    float a0[4], a1[4];
    #pragma unroll
    for (int q = 0; q < 4; ++q) { a0[q] = 0.f; a1[q] = 0.f; }
    for (int k4 = 0; k4 < 256; k4 += 4) {
      float w0[4], w1[4];
      #pragma unroll
      for (int u = 0; u < 4; ++u) {
        w0[u] = W2p[(k4 + u) * 128 + c2];
        w1[u] = W2p[(k4 + u) * 128 + c2 + 64];
      }
      #pragma unroll
      for (int q = 0; q < 4; ++q) {
        const float4 a = *(const float4*)&Z1[(eq * 4 + q) * 256 + k4];
        a0[q] = fmaf(a.x, w0[0], a0[q]); a0[q] = fmaf(a.y, w0[1], a0[q]);
        a0[q] = fmaf(a.z, w0[2], a0[q]); a0[q] = fmaf(a.w, w0[3], a0[q]);
        a1[q] = fmaf(a.x, w1[0], a1[q]); a1[q] = fmaf(a.y, w1[1], a1[q]);
        a1[q] = fmaf(a.z, w1[2], a1[q]); a1[q] = fmaf(a.w, w1[3], a1[q]);
      }
    }
    float bb0 = b2p[c2], bb1 = b2p[c2 + 64];
    #pragma unroll
    for (int q = 0; q < 4; ++q) {
      Z2[(eq * 4 + q) * 128 + c2] = a0[q] + bb0;
      Z2[(eq * 4 + q) * 128 + c2 + 64] = a1[q] + bb1;
    }
  }
  __syncthreads();

  // LN2 stats (128 per edge)
  {
    const int wv = tid >> 6, ln = tid & 63;
    for (int s = 0; s < 4; ++s) {
      int ei = wv * 4 + s;
      float v0 = Z2[ei * 128 + ln], v1 = Z2[ei * 128 + ln + 64];
      float sm = v0 + v1, sq = v0 * v0 + v1 * v1;
      #pragma unroll
      for (int off = 32; off > 0; off >>= 1) {
        sm += __shfl_down(sm, off);
        sq += __shfl_down(sq, off);
      }
      if (ln == 0) {
        float m = sm * (1.f / 128.f);
        float var = sq * (1.f / 128.f) - m * m;
        mu2[ei] = m; rs2[ei] = rsqrtf(var + 1e-5f);
      }
    }
  }
  __syncthreads();

  // epilogue: residual + store
  {
    const int j = tid & 127;
    const int ehf = tid >> 7;
    float g = g2p[j], bt = bt2p[j];
    #pragma unroll
    for (int s = 0; s < 8; ++s) {
      int ei = ehf * 8 + s;
      float z = (Z2[ei * 128 + j] - mu2[ei]) * rs2[ei] * g + bt;
      float res = A[ei * 384 + 256 + j];
      e[(size_t)(base + ei) * 128 + j] = res + z;
    }
  }
}

// ---------------- node MLP: h += LN(GELU(LN([h,agg]@W1+b1))@W2+b2) ----------------
__global__ __launch_bounds__(256) void k_node_mlp(
    float* __restrict__ h, const float* __restrict__ agg,
    const float* __restrict__ W1, const float* __restrict__ b1,
    const float* __restrict__ g1, const float* __restrict__ bt1,
    const float* __restrict__ W2, const float* __restrict__ b2,
    const float* __restrict__ g2, const float* __restrict__ bt2,
    int layer)
{
  __shared__ float A[16 * 256];
  __shared__ float Z1[16 * 256];
  __shared__ float Z2[16 * 128];
  __shared__ float mu1[16], rs1[16], mu2[16], rs2[16];

  const int tid = threadIdx.x;
  const int base = blockIdx.x * 16;
  const float* W1p = W1 + (size_t)layer * 256 * 256;
  const float* W2p = W2 + (size_t)layer * 256 * 128;
  const float* b1p = b1 + layer * 256;
  const float* g1p = g1 + layer * 256;
  const float* bt1p = bt1 + layer * 256;
  const float* b2p = b2 + layer * 128;
  const float* g2p = g2 + layer * 128;
  const float* bt2p = bt2 + layer * 128;

  for (int idx = tid; idx < 16 * 256; idx += 256) {
    int ni = idx >> 8;
    int c = idx & 255;
    float v;
    if (c < 128) v = h[(size_t)(base + ni) * 128 + c];
    else         v = agg[(size_t)(base + ni) * 128 + (c - 128)];
    A[idx] = v;
  }
  __syncthreads();

  // GEMM1: [16x256] @ [256x256]
  {
    const int oc = tid & 127;
    const int ehf = tid >> 7;
    float acc0[8], acc1[8];
    #pragma unroll
    for (int s = 0; s < 8; ++s) { acc0[s] = 0.f; acc1[s] = 0.f; }
    for (int k4 = 0; k4 < 256; k4 += 4) {
      float w0[4], w1[4];
      #pragma unroll
      for (int u = 0; u < 4; ++u) {
        w0[u] = W1p[(k4 + u) * 256 + oc];
        w1[u] = W1p[(k4 + u) * 256 + oc + 128];
      }
      #pragma unroll
      for (int s = 0; s < 8; ++s) {
        const float4 a = *(const float4*)&A[(ehf * 8 + s) * 256 + k4];
        acc0[s] = fmaf(a.x, w0[0], acc0[s]); acc0[s] = fmaf(a.y, w0[1], acc0[s]);
        acc0[s] = fmaf(a.z, w0[2], acc0[s]); acc0[s] = fmaf(a.w, w0[3], acc0[s]);
        acc1[s] = fmaf(a.x, w1[0], acc1[s]); acc1[s] = fmaf(a.y, w1[1], acc1[s]);
        acc1[s] = fmaf(a.z, w1[2], acc1[s]); acc1[s] = fmaf(a.w, w1[3], acc1[s]);
      }
    }
    float bb0 = b1p[oc], bb1 = b1p[oc + 128];
    #pragma unroll
    for (int s = 0; s < 8; ++s) {
      Z1[(ehf * 8 + s) * 256 + oc] = acc0[s] + bb0;
      Z1[(ehf * 8 + s) * 256 + oc + 128] = acc1[s] + bb1;
    }
  }
  __syncthreads();

  // LN1 stats
  {
    const int wv = tid >> 6, ln = tid & 63;
    for (int s = 0; s < 4; ++s) {
      int ei = wv * 4 + s;
      float v0 = Z1[ei * 256 + ln], v1 = Z1[ei * 256 + ln + 64];
      float v2 = Z1[ei * 256 + ln + 128], v3 = Z1[ei * 256 + ln + 192];
      float sm = v0 + v1 + v2 + v3;
      float sq = v0 * v0 + v1 * v1 + v2 * v2 + v3 * v3;
      #pragma unroll
      for (int off = 32; off > 0; off >>= 1) {
        sm += __shfl_down(sm, off);
        sq += __shfl_down(sq, off);
      }
      if (ln == 0) {
        float m = sm * (1.f / 256.f);
        float var = sq * (1.f / 256.f) - m * m;
        mu1[ei] = m; rs1[ei] = rsqrtf(var + 1e-5f);
      }
    }
  }
  __syncthreads();

  {
    float g = g1p[tid], bt = bt1p[tid];
    for (int ei = 0; ei < 16; ++ei) {
      float z = Z1[ei * 256 + tid];
      z = (z - mu1[ei]) * rs1[ei] * g + bt;
      Z1[ei * 256 + tid] = gelu_exact(z);
    }
  }
  __syncthreads();

  // GEMM2: [16x256] @ [256x128]
  {
    const int c2 = tid & 63;
    const int eq = tid >> 6;
    float a0[4], a1[4];
    #pragma unroll
    for (int q = 0; q < 4; ++q) { a0[q] = 0.f; a1[q] = 0.f; }
    for (int k4 = 0; k4 < 256; k4 += 4) {
      float w0[4], w1[4];
      #pragma unroll
      for (int u = 0; u < 4; ++u) {
        w0[u] = W2p[(k4 + u) * 128 + c2];
        w1[u] = W2p[(k4 + u) * 128 + c2 + 64];
      }
      #pragma unroll
      for (int q = 0; q < 4; ++q) {
        const float4 a = *(const float4*)&Z1[(eq * 4 + q) * 256 + k4];
        a0[q] = fmaf(a.x, w0[0], a0[q]); a0[q] = fmaf(a.y, w0[1], a0[q]);
        a0[q] = fmaf(a.z, w0[2], a0[q]); a0[q] = fmaf(a.w, w0[3], a0[q]);
        a1[q] = fmaf(a.x, w1[0], a1[q]); a1[q] = fmaf(a.y, w1[1], a1[q]);
        a1[q] = fmaf(a.z, w1[2], a1[q]); a1[q] = fmaf(a.w, w1[3], a1[q]);
      }
    }
    float bb0 = b2p[c2], bb1 = b2p[c2 + 64];
    #pragma unroll
    for (int q = 0; q < 4; ++q) {
      Z2[(eq * 4 + q) * 128 + c2] = a0[q] + bb0;
      Z2[(eq * 4 + q) * 128 + c2 + 64] = a1[q] + bb1;
    }
  }
  __syncthreads();

  // LN2 stats
  {
    const int wv = tid >> 6, ln = tid & 63;
    for (int s = 0; s < 4; ++s) {
      int ei = wv * 4 + s;
      float v0 = Z2[ei * 128 + ln], v1 = Z2[ei * 128 + ln + 64];
      float sm = v0 + v1, sq = v0 * v0 + v1 * v1;
      #pragma unroll
      for (int off = 32; off > 0; off >>= 1) {
        sm += __shfl_down(sm, off);
        sq += __shfl_down(sq, off);
      }
      if (ln == 0) {
        float m = sm * (1.f / 128.f);
        float var = sq * (1.f / 128.f) - m * m;
        mu2[ei] = m; rs2[ei] = rsqrtf(var + 1e-5f);
      }
    }
  }
  __syncthreads();

  // epilogue: residual + store h
  {
    const int j = tid & 127;
    const int ehf = tid >> 7;
    float g = g2p[j], bt = bt2p[j];
    #pragma unroll
    for (int s = 0; s < 8; ++s) {
      int ni = ehf * 8 + s;
      float z = (Z2[ni * 128 + j] - mu2[ni]) * rs2[ni] * g + bt;
      float res = A[ni * 256 + j];
      h[(size_t)(base + ni) * 128 + j] = res + z;
    }
  }
}

// ---------------- decoder: out = gelu(h@dW1+db1)@dW2+db2 ----------------
__global__ __launch_bounds__(128) void k_decoder(
    const float* __restrict__ h, const float* __restrict__ W1,
    const float* __restrict__ b1, const float* __restrict__ W2,
    const float* __restrict__ b2, float* __restrict__ out)
{
  const int n = blockIdx.x;
  const int j = threadIdx.x; // 128
  __shared__ float hs[128];
  __shared__ float z1s[128];
  hs[j] = h[(size_t)n * 128 + j];
  __syncthreads();
  float z = b1[j];
  for (int k = 0; k < 128; ++k) z = fmaf(hs[k], W1[k * 128 + j], z);
  z1s[j] = gelu_exact(z);
  __syncthreads();
  if (j < 4) {
    float o = b2[j];
    for (int k = 0; k < 128; ++k) o = fmaf(z1s[k], W2[k * 4 + j], o);
    out[n * 4 + j] = o;
  }
}

extern "C" void kernel_launch(void* const* d_in, const int* in_sizes, int n_in,
                              void* d_out, int out_size, void* d_ws, size_t ws_size,
                              hipStream_t stream) {
  const float* x     = (const float*)d_in[0];
  const int*   eidx  = (const int*)d_in[1];
  const float* ea    = (const float*)d_in[2];
  const float* encW  = (const float*)d_in[3];
  const float* encb  = (const float*)d_in[4];
  const float* encg  = (const float*)d_in[5];
  const float* encbt = (const float*)d_in[6];
  const float* eencW = (const float*)d_in[7];
  const float* eencb = (const float*)d_in[8];
  const float* eW1   = (const float*)d_in[9];
  const float* eb1   = (const float*)d_in[10];
  const float* eg1   = (const float*)d_in[11];
  const float* ebt1  = (const float*)d_in[12];
  const float* eW2   = (const float*)d_in[13];
  const float* eb2   = (const float*)d_in[14];
  const float* eg2   = (const float*)d_in[15];
  const float* ebt2  = (const float*)d_in[16];
  const float* nW1   = (const float*)d_in[17];
  const float* nb1   = (const float*)d_in[18];
  const float* ng1   = (const float*)d_in[19];
  const float* nbt1  = (const float*)d_in[20];
  const float* nW2   = (const float*)d_in[21];
  const float* nb2   = (const float*)d_in[22];
  const float* ng2   = (const float*)d_in[23];
  const float* nbt2  = (const float*)d_in[24];
  const float* dW1   = (const float*)d_in[25];
  const float* db1   = (const float*)d_in[26];
  const float* dW2   = (const float*)d_in[27];
  const float* db2   = (const float*)d_in[28];
  float* out = (float*)d_out;

  char* p = (char*)d_ws;
  float* h   = (float*)p; p += (size_t)NN * 128 * 4;
  float* e   = (float*)p; p += (size_t)EE * 128 * 4;
  float* agg = (float*)p; p += (size_t)NN * 128 * 4;
  int* cnt     = (int*)p; p += (size_t)NN * 4;
  int* rowptr  = (int*)p; p += (size_t)(NN + 1) * 4;
  int* fillp   = (int*)p; p += (size_t)NN * 4;
  int* edge_of = (int*)p; p += (size_t)EE * 4;

  k_encoder<<<NN, 128, 0, stream>>>(x, encW, encb, encg, encbt, h);
  k_edge_enc<<<(EE * 128) / 256, 256, 0, stream>>>(ea, eencW, eencb, e);
  k_zero_cnt<<<(NN + 255) / 256, 256, 0, stream>>>(cnt);
  k_count<<<EE / 256, 256, 0, stream>>>(eidx, cnt);
  k_scan<<<1, 256, 0, stream>>>(cnt, rowptr, fillp);
  k_fill<<<EE / 256, 256, 0, stream>>>(eidx, fillp, edge_of);

  for (int l = 0; l < L_LAYERS; ++l) {
    k_edge_mlp<<<EE / 16, 256, 0, stream>>>(h, e, eidx,
        eW1, eb1, eg1, ebt1, eW2, eb2, eg2, ebt2, l);
    k_agg<<<NN, 128, 0, stream>>>(e, rowptr, edge_of, agg);
    k_node_mlp<<<NN / 16, 256, 0, stream>>>(h, agg,
        nW1, nb1, ng1, nbt1, nW2, nb2, ng2, nbt2, l);
  }
  k_decoder<<<NN, 128, 0, stream>>>(h, dW1, db1, dW2, db2, out);
}

// Round 3
// 2436.313 us; speedup vs baseline: 3.5248x; 3.5248x over previous
//
#include <hip/hip_runtime.h>

#define L_LAYERS 10
#define NN 10000
#define EE 160000

typedef unsigned short ushort_t;
typedef unsigned int uint_t;
typedef __attribute__((ext_vector_type(8))) short bf16x8;
typedef __attribute__((ext_vector_type(4))) float floatx4;

__device__ __forceinline__ ushort_t f2b(float f) {
  uint_t u = __float_as_uint(f);
  u += 0x7FFFu + ((u >> 16) & 1u);
  return (ushort_t)(u >> 16);
}
__device__ __forceinline__ float gelu_exact(float x) {
  return 0.5f * x * (1.0f + erff(x * 0.7071067811865475f));
}
#define MFMA16x32(a, b, c) __builtin_amdgcn_mfma_f32_16x16x32_bf16((a), (b), (c), 0, 0, 0)

// ---------------- weight pack: W[L][K][N] fp32 -> P[L][K/32][N][32] bf16 ----------------
// inner 32 ordered so lane(n=lane&15, quad=lane>>4) reads its 8 k-values (k=ks*32+quad*8+j)
// as one contiguous 16B load.
__global__ __launch_bounds__(256) void k_pack_w(
    const float* __restrict__ W, ushort_t* __restrict__ P, int K, int N, int LKN)
{
  int idx = blockIdx.x * 256 + threadIdx.x;
  if (idx >= LKN) return;
  int n = idx % N;
  int t = idx / N;
  int k = t % K;
  int l = t / K;
  int ks = k >> 5, kk = k & 31;
  int Ks = K >> 5;
  P[(((size_t)((l * Ks + ks) * N + n)) << 5) + kk] = f2b(W[idx]);
}

// ---------------- encoder: h = gelu(LN(x @ W + b)) ----------------
__global__ __launch_bounds__(128) void k_encoder(
    const float* __restrict__ x, const float* __restrict__ W,
    const float* __restrict__ b, const float* __restrict__ g,
    const float* __restrict__ bt, float* __restrict__ h)
{
  const int n = blockIdx.x;
  const int j = threadIdx.x; // 128
  __shared__ float xs[7];
  __shared__ float red[4];
  if (j < 7) xs[j] = x[n * 7 + j];
  __syncthreads();
  float z = b[j];
  #pragma unroll
  for (int k = 0; k < 7; ++k) z = fmaf(xs[k], W[k * 128 + j], z);
  float sm = z, sq = z * z;
  #pragma unroll
  for (int off = 32; off > 0; off >>= 1) {
    sm += __shfl_down(sm, off);
    sq += __shfl_down(sq, off);
  }
  const int wv = j >> 6, ln = j & 63;
  if (ln == 0) { red[wv] = sm; red[2 + wv] = sq; }
  __syncthreads();
  float m = (red[0] + red[1]) * (1.0f / 128.0f);
  float var = (red[2] + red[3]) * (1.0f / 128.0f) - m * m;
  float zz = (z - m) * rsqrtf(var + 1e-5f) * g[j] + bt[j];
  h[(size_t)n * 128 + j] = gelu_exact(zz);
}

// ---------------- edge encoder: e = ea @ W + b ----------------
__global__ __launch_bounds__(256) void k_edge_enc(
    const float* __restrict__ ea, const float* __restrict__ W,
    const float* __restrict__ b, float* __restrict__ e)
{
  const int i = blockIdx.x * 256 + threadIdx.x; // over EE*128
  const int eid = i >> 7, j = i & 127;
  float z = b[j];
  #pragma unroll
  for (int k = 0; k < 8; ++k) z = fmaf(ea[eid * 8 + k], W[k * 128 + j], z);
  e[i] = z;
}

// ---------------- CSR build ----------------
__global__ void k_zero_cnt(int* __restrict__ cnt) {
  int i = blockIdx.x * 256 + threadIdx.x;
  if (i < NN) cnt[i] = 0;
}
__global__ void k_count(const int* __restrict__ eidx, int* __restrict__ cnt) {
  int i = blockIdx.x * 256 + threadIdx.x;
  atomicAdd(&cnt[eidx[EE + i]], 1);
}
__global__ __launch_bounds__(256) void k_scan(
    const int* __restrict__ cnt, int* __restrict__ rowptr, int* __restrict__ fillp)
{
  __shared__ int tot[256];
  __shared__ int off[257];
  const int t = threadIdx.x;
  const int C = 40; // 256*40 = 10240 >= NN
  int s = 0;
  int lo = t * C, hi = lo + C; if (hi > NN) hi = NN;
  for (int i = lo; i < hi; ++i) s += cnt[i];
  tot[t] = s;
  __syncthreads();
  if (t == 0) {
    int r = 0;
    for (int i = 0; i < 256; ++i) { off[i] = r; r += tot[i]; }
    off[256] = r;
  }
  __syncthreads();
  int r = off[t];
  for (int i = lo; i < hi; ++i) {
    rowptr[i] = r; fillp[i] = r;
    r += cnt[i];
  }
  if (t == 0) rowptr[NN] = off[256];
}
__global__ void k_fill(const int* __restrict__ eidx, int* __restrict__ fillp,
                       int* __restrict__ edge_of) {
  int i = blockIdx.x * 256 + threadIdx.x;
  int c = eidx[EE + i];
  int pos = atomicAdd(&fillp[c], 1);
  edge_of[pos] = i;
}

// ---------------- aggregation: agg[n] = mean of e over CSR ----------------
__global__ __launch_bounds__(128) void k_agg(
    const float* __restrict__ e, const int* __restrict__ rowptr,
    const int* __restrict__ edge_of, float* __restrict__ agg)
{
  const int n = blockIdx.x;
  const int j = threadIdx.x; // 128
  const int s = rowptr[n], en = rowptr[n + 1];
  float acc = 0.0f;
  for (int it = s; it < en; ++it) {
    int eid = edge_of[it];
    acc += e[(size_t)eid * 128 + j];
  }
  int c = en - s;
  float inv = 1.0f / (float)(c > 0 ? c : 1);
  agg[(size_t)n * 128 + j] = acc * inv;
}

// ---------------- edge MLP (MFMA): e += LN(GELU(LN([h_r,h_c,e]@W1+b1))@W2+b2) ----------------
// 32 edges/block, 4 waves; wave w owns cols [w*64,w*64+64) of GEMM1 and [w*32,w*32+32) of GEMM2.
// LDS ~43.5 KB -> 3 blocks/CU. A-tile stride 392 (=384+8 pad): 2-way bank aliasing only (free).
__global__ __launch_bounds__(256) void k_edge_mlp_mfma(
    const float* __restrict__ h, float* __restrict__ e,
    const int* __restrict__ eidx,
    const ushort_t* __restrict__ W1pk, const ushort_t* __restrict__ W2pk,
    const float* __restrict__ b1, const float* __restrict__ g1, const float* __restrict__ bt1,
    const float* __restrict__ b2, const float* __restrict__ g2, const float* __restrict__ bt2,
    int layer)
{
  __shared__ ushort_t A16[32 * 392];
  __shared__ ushort_t Z16[32 * 264];
  __shared__ float red_s[32 * 4], red_q[32 * 4];
  __shared__ float mu_s[32], rs_s[32];
  __shared__ int s_row[32], s_col[32];

  const int tid = threadIdx.x;
  const int base = blockIdx.x * 32;
  const ushort_t* W1p = W1pk + (size_t)layer * (12 * 256 * 32);
  const ushort_t* W2p = W2pk + (size_t)layer * (8 * 128 * 32);
  const float* b1p = b1 + layer * 256;
  const float* g1p = g1 + layer * 256;
  const float* bt1p = bt1 + layer * 256;
  const float* b2p = b2 + layer * 128;
  const float* g2p = g2 + layer * 128;
  const float* bt2p = bt2 + layer * 128;

  if (tid < 32) s_row[tid] = eidx[base + tid];
  else if (tid < 64) s_col[tid - 32] = eidx[EE + base + (tid - 32)];
  __syncthreads();

  // stage A as bf16: cols 0:128 = h[row], 128:256 = h[col], 256:384 = e
  #pragma unroll
  for (int i = 0; i < 12; ++i) {
    int idx = tid + i * 256;            // 0..3071 over (ei, c4) ; 96 float4 per edge
    int ei = idx / 96, c4 = idx - ei * 96;
    const float* src;
    if (c4 < 32)      src = h + (size_t)s_row[ei] * 128 + c4 * 4;
    else if (c4 < 64) src = h + (size_t)s_col[ei] * 128 + (c4 - 32) * 4;
    else              src = e + (size_t)(base + ei) * 128 + (c4 - 64) * 4;
    float4 v = *(const float4*)src;
    uint2 pv;
    pv.x = (uint_t)f2b(v.x) | ((uint_t)f2b(v.y) << 16);
    pv.y = (uint_t)f2b(v.z) | ((uint_t)f2b(v.w) << 16);
    *(uint2*)&A16[ei * 392 + c4 * 4] = pv;
  }
  __syncthreads();

  const int lane = tid & 63;
  const int wv = tid >> 6;
  const int ln15 = lane & 15;
  const int quad = lane >> 4;

  // ---- GEMM1: [32x384] @ [384x256] ----
  floatx4 acc[2][4];
  #pragma unroll
  for (int mi = 0; mi < 2; ++mi)
    #pragma unroll
    for (int ni = 0; ni < 4; ++ni) acc[mi][ni] = (floatx4){0.f, 0.f, 0.f, 0.f};

  const int nb1 = wv * 64;
  for (int ks = 0; ks < 12; ++ks) {
    bf16x8 a0 = *(const bf16x8*)&A16[ln15 * 392 + ks * 32 + quad * 8];
    bf16x8 a1 = *(const bf16x8*)&A16[(16 + ln15) * 392 + ks * 32 + quad * 8];
    #pragma unroll
    for (int ni = 0; ni < 4; ++ni) {
      bf16x8 b = *(const bf16x8*)&W1p[((size_t)(ks * 256 + nb1 + ni * 16 + ln15) << 5) + quad * 8];
      acc[0][ni] = MFMA16x32(a0, b, acc[0][ni]);
      acc[1][ni] = MFMA16x32(a1, b, acc[1][ni]);
    }
  }

  // bias + LN1 partials (sum over this wave's 64 cols per row)
  #pragma unroll
  for (int ni = 0; ni < 4; ++ni) {
    float bb = b1p[nb1 + ni * 16 + ln15];
    #pragma unroll
    for (int mi = 0; mi < 2; ++mi)
      #pragma unroll
      for (int r = 0; r < 4; ++r) acc[mi][ni][r] += bb;
  }
  #pragma unroll
  for (int mi = 0; mi < 2; ++mi)
    #pragma unroll
    for (int r = 0; r < 4; ++r) {
      float v = 0.f, u = 0.f;
      #pragma unroll
      for (int ni = 0; ni < 4; ++ni) { float x = acc[mi][ni][r]; v += x; u += x * x; }
      #pragma unroll
      for (int off = 1; off < 16; off <<= 1) { v += __shfl_xor(v, off); u += __shfl_xor(u, off); }
      if (ln15 == 0) {
        int row = mi * 16 + quad * 4 + r;
        red_s[row * 4 + wv] = v; red_q[row * 4 + wv] = u;
      }
    }
  __syncthreads();
  if (tid < 32) {
    float S = red_s[tid * 4] + red_s[tid * 4 + 1] + red_s[tid * 4 + 2] + red_s[tid * 4 + 3];
    float Q = red_q[tid * 4] + red_q[tid * 4 + 1] + red_q[tid * 4 + 2] + red_q[tid * 4 + 3];
    float m = S * (1.f / 256.f);
    float var = Q * (1.f / 256.f) - m * m;
    mu_s[tid] = m; rs_s[tid] = rsqrtf(var + 1e-5f);
  }
  __syncthreads();

  // normalize + gelu -> Z (bf16, A-layout for GEMM2)
  #pragma unroll
  for (int ni = 0; ni < 4; ++ni) {
    int col = nb1 + ni * 16 + ln15;
    float gg = g1p[col], bb = bt1p[col];
    #pragma unroll
    for (int mi = 0; mi < 2; ++mi)
      #pragma unroll
      for (int r = 0; r < 4; ++r) {
        int row = mi * 16 + quad * 4 + r;
        float z = (acc[mi][ni][r] - mu_s[row]) * rs_s[row] * gg + bb;
        Z16[row * 264 + col] = f2b(gelu_exact(z));
      }
  }
  __syncthreads();

  // ---- GEMM2: [32x256] @ [256x128] ----
  floatx4 c2[2][2];
  #pragma unroll
  for (int mi = 0; mi < 2; ++mi)
    #pragma unroll
    for (int ni = 0; ni < 2; ++ni) c2[mi][ni] = (floatx4){0.f, 0.f, 0.f, 0.f};

  const int nb2 = wv * 32;
  for (int ks = 0; ks < 8; ++ks) {
    bf16x8 a0 = *(const bf16x8*)&Z16[ln15 * 264 + ks * 32 + quad * 8];
    bf16x8 a1 = *(const bf16x8*)&Z16[(16 + ln15) * 264 + ks * 32 + quad * 8];
    #pragma unroll
    for (int ni = 0; ni < 2; ++ni) {
      bf16x8 b = *(const bf16x8*)&W2p[((size_t)(ks * 128 + nb2 + ni * 16 + ln15) << 5) + quad * 8];
      c2[0][ni] = MFMA16x32(a0, b, c2[0][ni]);
      c2[1][ni] = MFMA16x32(a1, b, c2[1][ni]);
    }
  }

  // bias + LN2 partials (32 cols per wave)
  #pragma unroll
  for (int ni = 0; ni < 2; ++ni) {
    float bb = b2p[nb2 + ni * 16 + ln15];
    #pragma unroll
    for (int mi = 0; mi < 2; ++mi)
      #pragma unroll
      for (int r = 0; r < 4; ++r) c2[mi][ni][r] += bb;
  }
  #pragma unroll
  for (int mi = 0; mi < 2; ++mi)
    #pragma unroll
    for (int r = 0; r < 4; ++r) {
      float v = 0.f, u = 0.f;
      #pragma unroll
      for (int ni = 0; ni < 2; ++ni) { float x = c2[mi][ni][r]; v += x; u += x * x; }
      #pragma unroll
      for (int off = 1; off < 16; off <<= 1) { v += __shfl_xor(v, off); u += __shfl_xor(u, off); }
      if (ln15 == 0) {
        int row = mi * 16 + quad * 4 + r;
        red_s[row * 4 + wv] = v; red_q[row * 4 + wv] = u;
      }
    }
  __syncthreads();
  if (tid < 32) {
    float S = red_s[tid * 4] + red_s[tid * 4 + 1] + red_s[tid * 4 + 2] + red_s[tid * 4 + 3];
    float Q = red_q[tid * 4] + red_q[tid * 4 + 1] + red_q[tid * 4 + 2] + red_q[tid * 4 + 3];
    float m = S * (1.f / 128.f);
    float var = Q * (1.f / 128.f) - m * m;
    mu_s[tid] = m; rs_s[tid] = rsqrtf(var + 1e-5f);
  }
  __syncthreads();

  // epilogue: residual (fp32 re-read) + store
  #pragma unroll
  for (int ni = 0; ni < 2; ++ni) {
    int col = nb2 + ni * 16 + ln15;
    float gg = g2p[col], bb = bt2p[col];
    #pragma unroll
    for (int mi = 0; mi < 2; ++mi)
      #pragma unroll
      for (int r = 0; r < 4; ++r) {
        int row = mi * 16 + quad * 4 + r;
        float z = (c2[mi][ni][r] - mu_s[row]) * rs_s[row] * gg + bb;
        size_t gi = (size_t)(base + row) * 128 + col;
        e[gi] = e[gi] + z;
      }
  }
}

// ---------------- node MLP (MFMA): h += LN(GELU(LN([h,agg]@W1+b1))@W2+b2) ----------------
__global__ __launch_bounds__(256) void k_node_mlp_mfma(
    float* __restrict__ h, const float* __restrict__ agg,
    const ushort_t* __restrict__ W1pk, const ushort_t* __restrict__ W2pk,
    const float* __restrict__ b1, const float* __restrict__ g1, const float* __restrict__ bt1,
    const float* __restrict__ b2, const float* __restrict__ g2, const float* __restrict__ bt2,
    int layer)
{
  __shared__ ushort_t A16[32 * 264];
  __shared__ ushort_t Z16[32 * 264];
  __shared__ float red_s[32 * 4], red_q[32 * 4];
  __shared__ float mu_s[32], rs_s[32];

  const int tid = threadIdx.x;
  const int base = blockIdx.x * 32;
  const ushort_t* W1p = W1pk + (size_t)layer * (8 * 256 * 32);
  const ushort_t* W2p = W2pk + (size_t)layer * (8 * 128 * 32);
  const float* b1p = b1 + layer * 256;
  const float* g1p = g1 + layer * 256;
  const float* bt1p = bt1 + layer * 256;
  const float* b2p = b2 + layer * 128;
  const float* g2p = g2 + layer * 128;
  const float* bt2p = bt2 + layer * 128;

  // stage A as bf16: cols 0:128 = h, 128:256 = agg  (zero-pad rows >= NN)
  #pragma unroll
  for (int i = 0; i < 8; ++i) {
    int idx = tid + i * 256;            // 0..2047 over (ni_, c4); 64 float4 per node
    int ni_ = idx >> 6, c4 = idx & 63;
    int g = base + ni_;
    float4 v = make_float4(0.f, 0.f, 0.f, 0.f);
    if (g < NN) {
      const float* src = (c4 < 32) ? (h + (size_t)g * 128 + c4 * 4)
                                   : (agg + (size_t)g * 128 + (c4 - 32) * 4);
      v = *(const float4*)src;
    }
    uint2 pv;
    pv.x = (uint_t)f2b(v.x) | ((uint_t)f2b(v.y) << 16);
    pv.y = (uint_t)f2b(v.z) | ((uint_t)f2b(v.w) << 16);
    *(uint2*)&A16[ni_ * 264 + c4 * 4] = pv;
  }
  __syncthreads();

  const int lane = tid & 63;
  const int wv = tid >> 6;
  const int ln15 = lane & 15;
  const int quad = lane >> 4;

  // ---- GEMM1: [32x256] @ [256x256] ----
  floatx4 acc[2][4];
  #pragma unroll
  for (int mi = 0; mi < 2; ++mi)
    #pragma unroll
    for (int ni = 0; ni < 4; ++ni) acc[mi][ni] = (floatx4){0.f, 0.f, 0.f, 0.f};

  const int nb1 = wv * 64;
  for (int ks = 0; ks < 8; ++ks) {
    bf16x8 a0 = *(const bf16x8*)&A16[ln15 * 264 + ks * 32 + quad * 8];
    bf16x8 a1 = *(const bf16x8*)&A16[(16 + ln15) * 264 + ks * 32 + quad * 8];
    #pragma unroll
    for (int ni = 0; ni < 4; ++ni) {
      bf16x8 b = *(const bf16x8*)&W1p[((size_t)(ks * 256 + nb1 + ni * 16 + ln15) << 5) + quad * 8];
      acc[0][ni] = MFMA16x32(a0, b, acc[0][ni]);
      acc[1][ni] = MFMA16x32(a1, b, acc[1][ni]);
    }
  }

  #pragma unroll
  for (int ni = 0; ni < 4; ++ni) {
    float bb = b1p[nb1 + ni * 16 + ln15];
    #pragma unroll
    for (int mi = 0; mi < 2; ++mi)
      #pragma unroll
      for (int r = 0; r < 4; ++r) acc[mi][ni][r] += bb;
  }
  #pragma unroll
  for (int mi = 0; mi < 2; ++mi)
    #pragma unroll
    for (int r = 0; r < 4; ++r) {
      float v = 0.f, u = 0.f;
      #pragma unroll
      for (int ni = 0; ni < 4; ++ni) { float x = acc[mi][ni][r]; v += x; u += x * x; }
      #pragma unroll
      for (int off = 1; off < 16; off <<= 1) { v += __shfl_xor(v, off); u += __shfl_xor(u, off); }
      if (ln15 == 0) {
        int row = mi * 16 + quad * 4 + r;
        red_s[row * 4 + wv] = v; red_q[row * 4 + wv] = u;
      }
    }
  __syncthreads();
  if (tid < 32) {
    float S = red_s[tid * 4] + red_s[tid * 4 + 1] + red_s[tid * 4 + 2] + red_s[tid * 4 + 3];
    float Q = red_q[tid * 4] + red_q[tid * 4 + 1] + red_q[tid * 4 + 2] + red_q[tid * 4 + 3];
    float m = S * (1.f / 256.f);
    float var = Q * (1.f / 256.f) - m * m;
    mu_s[tid] = m; rs_s[tid] = rsqrtf(var + 1e-5f);
  }
  __syncthreads();

  #pragma unroll
  for (int ni = 0; ni < 4; ++ni) {
    int col = nb1 + ni * 16 + ln15;
    float gg = g1p[col], bb = bt1p[col];
    #pragma unroll
    for (int mi = 0; mi < 2; ++mi)
      #pragma unroll
      for (int r = 0; r < 4; ++r) {
        int row = mi * 16 + quad * 4 + r;
        float z = (acc[mi][ni][r] - mu_s[row]) * rs_s[row] * gg + bb;
        Z16[row * 264 + col] = f2b(gelu_exact(z));
      }
  }
  __syncthreads();

  // ---- GEMM2: [32x256] @ [256x128] ----
  floatx4 c2[2][2];
  #pragma unroll
  for (int mi = 0; mi < 2; ++mi)
    #pragma unroll
    for (int ni = 0; ni < 2; ++ni) c2[mi][ni] = (floatx4){0.f, 0.f, 0.f, 0.f};

  const int nb2 = wv * 32;
  for (int ks = 0; ks < 8; ++ks) {
    bf16x8 a0 = *(const bf16x8*)&Z16[ln15 * 264 + ks * 32 + quad * 8];
    bf16x8 a1 = *(const bf16x8*)&Z16[(16 + ln15) * 264 + ks * 32 + quad * 8];
    #pragma unroll
    for (int ni = 0; ni < 2; ++ni) {
      bf16x8 b = *(const bf16x8*)&W2p[((size_t)(ks * 128 + nb2 + ni * 16 + ln15) << 5) + quad * 8];
      c2[0][ni] = MFMA16x32(a0, b, c2[0][ni]);
      c2[1][ni] = MFMA16x32(a1, b, c2[1][ni]);
    }
  }

  #pragma unroll
  for (int ni = 0; ni < 2; ++ni) {
    float bb = b2p[nb2 + ni * 16 + ln15];
    #pragma unroll
    for (int mi = 0; mi < 2; ++mi)
      #pragma unroll
      for (int r = 0; r < 4; ++r) c2[mi][ni][r] += bb;
  }
  #pragma unroll
  for (int mi = 0; mi < 2; ++mi)
    #pragma unroll
    for (int r = 0; r < 4; ++r) {
      float v = 0.f, u = 0.f;
      #pragma unroll
      for (int ni = 0; ni < 2; ++ni) { float x = c2[mi][ni][r]; v += x; u += x * x; }
      #pragma unroll
      for (int off = 1; off < 16; off <<= 1) { v += __shfl_xor(v, off); u += __shfl_xor(u, off); }
      if (ln15 == 0) {
        int row = mi * 16 + quad * 4 + r;
        red_s[row * 4 + wv] = v; red_q[row * 4 + wv] = u;
      }
    }
  __syncthreads();
  if (tid < 32) {
    float S = red_s[tid * 4] + red_s[tid * 4 + 1] + red_s[tid * 4 + 2] + red_s[tid * 4 + 3];
    float Q = red_q[tid * 4] + red_q[tid * 4 + 1] + red_q[tid * 4 + 2] + red_q[tid * 4 + 3];
    float m = S * (1.f / 128.f);
    float var = Q * (1.f / 128.f) - m * m;
    mu_s[tid] = m; rs_s[tid] = rsqrtf(var + 1e-5f);
  }
  __syncthreads();

  #pragma unroll
  for (int ni = 0; ni < 2; ++ni) {
    int col = nb2 + ni * 16 + ln15;
    float gg = g2p[col], bb = bt2p[col];
    #pragma unroll
    for (int mi = 0; mi < 2; ++mi)
      #pragma unroll
      for (int r = 0; r < 4; ++r) {
        int row = mi * 16 + quad * 4 + r;
        int g = base + row;
        if (g < NN) {
          float z = (c2[mi][ni][r] - mu_s[row]) * rs_s[row] * gg + bb;
          size_t gi = (size_t)g * 128 + col;
          h[gi] = h[gi] + z;
        }
      }
  }
}

// ---------------- decoder: out = gelu(h@dW1+db1)@dW2+db2 ----------------
__global__ __launch_bounds__(128) void k_decoder(
    const float* __restrict__ h, const float* __restrict__ W1,
    const float* __restrict__ b1, const float* __restrict__ W2,
    const float* __restrict__ b2, float* __restrict__ out)
{
  const int n = blockIdx.x;
  const int j = threadIdx.x; // 128
  __shared__ float hs[128];
  __shared__ float z1s[128];
  hs[j] = h[(size_t)n * 128 + j];
  __syncthreads();
  float z = b1[j];
  for (int k = 0; k < 128; ++k) z = fmaf(hs[k], W1[k * 128 + j], z);
  z1s[j] = gelu_exact(z);
  __syncthreads();
  if (j < 4) {
    float o = b2[j];
    for (int k = 0; k < 128; ++k) o = fmaf(z1s[k], W2[k * 4 + j], o);
    out[n * 4 + j] = o;
  }
}

static inline char* align_up(char* p, size_t a) {
  return (char*)(((uintptr_t)p + (a - 1)) & ~(uintptr_t)(a - 1));
}

extern "C" void kernel_launch(void* const* d_in, const int* in_sizes, int n_in,
                              void* d_out, int out_size, void* d_ws, size_t ws_size,
                              hipStream_t stream) {
  const float* x     = (const float*)d_in[0];
  const int*   eidx  = (const int*)d_in[1];
  const float* ea    = (const float*)d_in[2];
  const float* encW  = (const float*)d_in[3];
  const float* encb  = (const float*)d_in[4];
  const float* encg  = (const float*)d_in[5];
  const float* encbt = (const float*)d_in[6];
  const float* eencW = (const float*)d_in[7];
  const float* eencb = (const float*)d_in[8];
  const float* eW1   = (const float*)d_in[9];
  const float* eb1   = (const float*)d_in[10];
  const float* eg1   = (const float*)d_in[11];
  const float* ebt1  = (const float*)d_in[12];
  const float* eW2   = (const float*)d_in[13];
  const float* eb2   = (const float*)d_in[14];
  const float* eg2   = (const float*)d_in[15];
  const float* ebt2  = (const float*)d_in[16];
  const float* nW1   = (const float*)d_in[17];
  const float* nb1   = (const float*)d_in[18];
  const float* ng1   = (const float*)d_in[19];
  const float* nbt1  = (const float*)d_in[20];
  const float* nW2   = (const float*)d_in[21];
  const float* nb2   = (const float*)d_in[22];
  const float* ng2   = (const float*)d_in[23];
  const float* nbt2  = (const float*)d_in[24];
  const float* dW1   = (const float*)d_in[25];
  const float* db1   = (const float*)d_in[26];
  const float* dW2   = (const float*)d_in[27];
  const float* db2   = (const float*)d_in[28];
  float* out = (float*)d_out;

  char* p = (char*)d_ws;
  float* h   = (float*)p; p += (size_t)NN * 128 * 4;
  float* e   = (float*)p; p += (size_t)EE * 128 * 4;
  float* agg = (float*)p; p += (size_t)NN * 128 * 4;
  int* cnt     = (int*)p; p += (size_t)NN * 4;
  int* rowptr  = (int*)p; p += (size_t)(NN + 1) * 4;
  int* fillp   = (int*)p; p += (size_t)NN * 4;
  int* edge_of = (int*)p; p += (size_t)EE * 4;
  p = align_up(p, 256);
  ushort_t* eW1pk = (ushort_t*)p; p += (size_t)L_LAYERS * 12 * 256 * 32 * 2;
  p = align_up(p, 256);
  ushort_t* eW2pk = (ushort_t*)p; p += (size_t)L_LAYERS * 8 * 128 * 32 * 2;
  p = align_up(p, 256);
  ushort_t* nW1pk = (ushort_t*)p; p += (size_t)L_LAYERS * 8 * 256 * 32 * 2;
  p = align_up(p, 256);
  ushort_t* nW2pk = (ushort_t*)p; p += (size_t)L_LAYERS * 8 * 128 * 32 * 2;

  // weight pre-pack (bf16, MFMA B-fragment order)
  {
    int n1 = L_LAYERS * 384 * 256;
    k_pack_w<<<(n1 + 255) / 256, 256, 0, stream>>>(eW1, eW1pk, 384, 256, n1);
    int n2 = L_LAYERS * 256 * 128;
    k_pack_w<<<(n2 + 255) / 256, 256, 0, stream>>>(eW2, eW2pk, 256, 128, n2);
    int n3 = L_LAYERS * 256 * 256;
    k_pack_w<<<(n3 + 255) / 256, 256, 0, stream>>>(nW1, nW1pk, 256, 256, n3);
    int n4 = L_LAYERS * 256 * 128;
    k_pack_w<<<(n4 + 255) / 256, 256, 0, stream>>>(nW2, nW2pk, 256, 128, n4);
  }

  k_encoder<<<NN, 128, 0, stream>>>(x, encW, encb, encg, encbt, h);
  k_edge_enc<<<(EE * 128) / 256, 256, 0, stream>>>(ea, eencW, eencb, e);
  k_zero_cnt<<<(NN + 255) / 256, 256, 0, stream>>>(cnt);
  k_count<<<EE / 256, 256, 0, stream>>>(eidx, cnt);
  k_scan<<<1, 256, 0, stream>>>(cnt, rowptr, fillp);
  k_fill<<<EE / 256, 256, 0, stream>>>(eidx, fillp, edge_of);

  for (int l = 0; l < L_LAYERS; ++l) {
    k_edge_mlp_mfma<<<EE / 32, 256, 0, stream>>>(h, e, eidx,
        eW1pk, eW2pk, eb1, eg1, ebt1, eb2, eg2, ebt2, l);
    k_agg<<<NN, 128, 0, stream>>>(e, rowptr, edge_of, agg);
    k_node_mlp_mfma<<<(NN + 31) / 32, 256, 0, stream>>>(h, agg,
        nW1pk, nW2pk, nb1, ng1, nbt1, nb2, ng2, nbt2, l);
  }
  k_decoder<<<NN, 128, 0, stream>>>(h, dW1, db1, dW2, db2, out);
}